// Round 2
// baseline (193.748 us; speedup 1.0000x reference)
//
#include <hip/hip_runtime.h>
#include <stdint.h>

#define MDIM 4096
#define NDIM 4096
#define KDIM 4096

typedef __bf16 bf16x8 __attribute__((ext_vector_type(8)));
typedef float f32x4 __attribute__((ext_vector_type(4)));

__device__ __forceinline__ uint32_t f32_to_bf16(float f) {
    union { float f; uint32_t u; } v; v.f = f;
    return (v.u + 0x7FFFu + ((v.u >> 16) & 1u)) >> 16;
}

#define GLDS16(gp, lp) \
    __builtin_amdgcn_global_load_lds((const __attribute__((address_space(1))) void*)(gp), \
                                     (__attribute__((address_space(3))) void*)(lp), 16, 0, 0)

// ---------------------------------------------------------------------------
// Dequant. NOTE: harness pushes integer inputs as int32 — W_q is 8388608
// int32 values, each one packed byte (0..255).
// w_uint[j] = high nibble of Wq[j] for j<8388608, low nibble of Wq[j-8388608]
// => W row o<2048: high nibbles of Wq[o*4096+i]; row o>=2048: low nibbles of
// Wq[(o-2048)*4096+i]. group g = o*64 + i/64 (full o).
// Each thread: 8 int32 -> 8 bf16 to row o and 8 bf16 to row o+2048.
// ---------------------------------------------------------------------------
__global__ void dq_kernel(const int* __restrict__ Wq,
                          const float* __restrict__ scale,
                          const float* __restrict__ zero,
                          uint16_t* __restrict__ Wb) {
    int t = blockIdx.x * 256 + threadIdx.x;      // 1048576 threads
    int o  = t >> 9;                              // packed row (0..2047)
    int i0 = (t & 511) << 3;                      // col start (8-aligned)
    const uint4* wp = (const uint4*)Wq;
    uint4 pa = wp[t * 2], pb = wp[t * 2 + 1];
    uint32_t v[8] = {pa.x, pa.y, pa.z, pa.w, pb.x, pb.y, pb.z, pb.w};
    int gh = (o << 6) + (i0 >> 6);
    int gl = gh + (2048 << 6);
    float sh = scale[gh], zh = zero[gh];
    float sl = scale[gl], zl = zero[gl];
    uint32_t hw[4], lw[4];
#pragma unroll
    for (int p = 0; p < 4; ++p) {
        uint32_t b0 = v[p * 2], b1 = v[p * 2 + 1];
        uint32_t h0 = f32_to_bf16(((float)((b0 >> 4) & 15u) - zh) * sh);
        uint32_t h1 = f32_to_bf16(((float)((b1 >> 4) & 15u) - zh) * sh);
        uint32_t l0 = f32_to_bf16(((float)(b0 & 15u) - zl) * sl);
        uint32_t l1 = f32_to_bf16(((float)(b1 & 15u) - zl) * sl);
        hw[p] = h0 | (h1 << 16);
        lw[p] = l0 | (l1 << 16);
    }
    uint4 hv = {hw[0], hw[1], hw[2], hw[3]};
    uint4 lv = {lw[0], lw[1], lw[2], lw[3]};
    *(uint4*)&Wb[(size_t)o * KDIM + i0]          = hv;
    *(uint4*)&Wb[(size_t)(o + 2048) * KDIM + i0] = lv;
}

// ---------------------------------------------------------------------------
// x fp32 -> bf16, 8 elems/thread
// ---------------------------------------------------------------------------
__global__ void xc_kernel(const float* __restrict__ x, uint16_t* __restrict__ xb) {
    int t = blockIdx.x * 256 + threadIdx.x;      // 2097152 threads
    const float4* xp = (const float4*)x;
    float4 a = xp[t * 2], b = xp[t * 2 + 1];
    uint4 o;
    o.x = f32_to_bf16(a.x) | (f32_to_bf16(a.y) << 16);
    o.y = f32_to_bf16(a.z) | (f32_to_bf16(a.w) << 16);
    o.z = f32_to_bf16(b.x) | (f32_to_bf16(b.y) << 16);
    o.w = f32_to_bf16(b.z) | (f32_to_bf16(b.w) << 16);
    ((uint4*)xb)[t] = o;
}

// ---------------------------------------------------------------------------
// GEMM: C[M][N] fp32 = A[M][K]bf16 * B[N][K]bf16^T  (m97 structure:
// 128x128 tile, BK=32, 4 waves of 64x64, global_load_lds w=16, 2-barrier loop)
// ---------------------------------------------------------------------------
__global__ void gemm_kernel(const uint16_t* __restrict__ A,
                            const uint16_t* __restrict__ B,
                            float* __restrict__ C) {
    __shared__ uint16_t As[128 * 32];   // [row][k], 64B rows
    __shared__ uint16_t Bs[128 * 32];

    const int tid  = threadIdx.x;
    const int wave = tid >> 6;
    const int lane = tid & 63;
    const int bm0 = blockIdx.y * 128;
    const int bn0 = blockIdx.x * 128;
    const int wr = wave >> 1, wc = wave & 1;

    // staging: chunk c (0..7) = 16 rows; lane covers row 16c + l/4, elems (l%4)*8
    const int srow = lane >> 2;
    const int scol = (lane & 3) << 3;

    f32x4 acc[4][4];
#pragma unroll
    for (int i = 0; i < 4; ++i)
#pragma unroll
        for (int j = 0; j < 4; ++j) {
            f32x4 z = {0.f, 0.f, 0.f, 0.f};
            acc[i][j] = z;
        }

    const uint16_t* Ab = A + (size_t)bm0 * KDIM;
    const uint16_t* Bb = B + (size_t)bn0 * KDIM;

    const int fr = lane & 15;            // fragment row (A) / row (B^T)
    const int kk = (lane >> 4) << 3;     // k offset 0/8/16/24

    for (int k0 = 0; k0 < KDIM; k0 += 32) {
        __syncthreads();                 // all waves done reading LDS
#pragma unroll
        for (int c = 0; c < 2; ++c) {
            int chunk = wave * 2 + c;
            int row = chunk * 16 + srow;
            GLDS16(Ab + (size_t)row * KDIM + k0 + scol, &As[chunk * 512]);
            GLDS16(Bb + (size_t)row * KDIM + k0 + scol, &Bs[chunk * 512]);
        }
        __syncthreads();                 // compiler drains vmcnt before barrier

        bf16x8 af[4], bfr[4];
#pragma unroll
        for (int m = 0; m < 4; ++m)
            af[m] = *(const bf16x8*)&As[(wr * 64 + m * 16 + fr) * 32 + kk];
#pragma unroll
        for (int n = 0; n < 4; ++n)
            bfr[n] = *(const bf16x8*)&Bs[(wc * 64 + n * 16 + fr) * 32 + kk];
#pragma unroll
        for (int m = 0; m < 4; ++m)
#pragma unroll
            for (int n = 0; n < 4; ++n)
                acc[m][n] = __builtin_amdgcn_mfma_f32_16x16x32_bf16(
                    af[m], bfr[n], acc[m][n], 0, 0, 0);
    }

    // epilogue: D lane layout col=lane&15, row=4*(lane>>4)+r  [m89/m91]
    const int cn = lane & 15;
    const int r0 = (lane >> 4) * 4;
#pragma unroll
    for (int m = 0; m < 4; ++m)
#pragma unroll
        for (int n = 0; n < 4; ++n)
#pragma unroll
            for (int r = 0; r < 4; ++r) {
                int row = bm0 + wr * 64 + m * 16 + r0 + r;
                int col = bn0 + wc * 64 + n * 16 + cn;
                C[(size_t)row * NDIM + col] = acc[m][n][r];
            }
}

extern "C" void kernel_launch(void* const* d_in, const int* in_sizes, int n_in,
                              void* d_out, int out_size, void* d_ws, size_t ws_size,
                              hipStream_t stream) {
    const float* x     = (const float*)d_in[0];
    const int*   Wq    = (const int*)d_in[1];      // uint8 pushed as int32
    const float* scale = (const float*)d_in[2];
    const float* zero  = (const float*)d_in[3];
    float* out = (float*)d_out;

    uint16_t* Wb = (uint16_t*)d_ws;                                     // 32 MB
    uint16_t* xb = (uint16_t*)((char*)d_ws + (size_t)32 * 1024 * 1024); // 32 MB

    hipLaunchKernelGGL(dq_kernel, dim3(4096), dim3(256), 0, stream, Wq, scale, zero, Wb);
    hipLaunchKernelGGL(xc_kernel, dim3(8192), dim3(256), 0, stream, x, xb);
    hipLaunchKernelGGL(gemm_kernel, dim3(32, 32), dim3(256), 0, stream, xb, Wb, out);
}

// Round 3
// 150.871 us; speedup vs baseline: 1.2842x; 1.2842x over previous
//
#include <hip/hip_runtime.h>
#include <stdint.h>

#define MD 4096
#define ND 4096
#define KD 4096
#define BK 64
#define NT (KD / BK)   // 64 K-tiles

typedef __bf16 bf16x8 __attribute__((ext_vector_type(8)));
typedef float f32x4 __attribute__((ext_vector_type(4)));

__device__ __forceinline__ uint32_t f32_to_bf16(float f) {
    union { float f; uint32_t u; } v; v.f = f;
    return (v.u + 0x7FFFu + ((v.u >> 16) & 1u)) >> 16;
}

#define GLDS16(gp, lp) \
    __builtin_amdgcn_global_load_lds((const __attribute__((address_space(1))) void*)(gp), \
                                     (__attribute__((address_space(3))) void*)(lp), 16, 0, 0)

// ---------------------------------------------------------------------------
// Dequant (W_q arrives as int32, one packed byte each).
// W row o<2048: high nibbles of Wq[o*4096+i]; row o>=2048: low nibbles.
// group g = o*64 + i/64.
// ---------------------------------------------------------------------------
__global__ void dq_kernel(const int* __restrict__ Wq,
                          const float* __restrict__ scale,
                          const float* __restrict__ zero,
                          uint16_t* __restrict__ Wb) {
    int t = blockIdx.x * 256 + threadIdx.x;      // 1048576 threads
    int o  = t >> 9;
    int i0 = (t & 511) << 3;
    const uint4* wp = (const uint4*)Wq;
    uint4 pa = wp[t * 2], pb = wp[t * 2 + 1];
    uint32_t v[8] = {pa.x, pa.y, pa.z, pa.w, pb.x, pb.y, pb.z, pb.w};
    int gh = (o << 6) + (i0 >> 6);
    int gl = gh + (2048 << 6);
    float sh = scale[gh], zh = zero[gh];
    float sl = scale[gl], zl = zero[gl];
    uint32_t hw[4], lw[4];
#pragma unroll
    for (int p = 0; p < 4; ++p) {
        uint32_t b0 = v[p * 2], b1 = v[p * 2 + 1];
        uint32_t h0 = f32_to_bf16(((float)((b0 >> 4) & 15u) - zh) * sh);
        uint32_t h1 = f32_to_bf16(((float)((b1 >> 4) & 15u) - zh) * sh);
        uint32_t l0 = f32_to_bf16(((float)(b0 & 15u) - zl) * sl);
        uint32_t l1 = f32_to_bf16(((float)(b1 & 15u) - zl) * sl);
        hw[p] = h0 | (h1 << 16);
        lw[p] = l0 | (l1 << 16);
    }
    uint4 hv = {hw[0], hw[1], hw[2], hw[3]};
    uint4 lv = {lw[0], lw[1], lw[2], lw[3]};
    *(uint4*)&Wb[(size_t)o * KD + i0]          = hv;
    *(uint4*)&Wb[(size_t)(o + 2048) * KD + i0] = lv;
}

__global__ void xc_kernel(const float* __restrict__ x, uint16_t* __restrict__ xb) {
    int t = blockIdx.x * 256 + threadIdx.x;
    const float4* xp = (const float4*)x;
    float4 a = xp[t * 2], b = xp[t * 2 + 1];
    uint4 o;
    o.x = f32_to_bf16(a.x) | (f32_to_bf16(a.y) << 16);
    o.y = f32_to_bf16(a.z) | (f32_to_bf16(a.w) << 16);
    o.z = f32_to_bf16(b.x) | (f32_to_bf16(b.y) << 16);
    o.w = f32_to_bf16(b.z) | (f32_to_bf16(b.w) << 16);
    ((uint4*)xb)[t] = o;
}

// ---------------------------------------------------------------------------
// 256x256 tile, BK=64, 8 waves (2Mx4N, each 128x64), 4-phase/K-tile schedule,
// counted vmcnt(4), LDS XOR swizzle, setprio, XCD swizzle.
// LDS region(buf,mat,kh) = 256 rows x 32 cols bf16 (16 KiB); 8 regions=128 KiB.
// Phase (kh,ch): ds_read frags; stage one quarter (2 gload_lds); bar;
// lgkm0; 16 MFMA; [vmcnt(4) at kh-phase ends]; bar.
// ---------------------------------------------------------------------------
#define BAR()  asm volatile("s_barrier" ::: "memory")
#define LGKM0() do { asm volatile("s_waitcnt lgkmcnt(0)" ::: "memory"); \
                     __builtin_amdgcn_sched_barrier(0); } while (0)
#define VM(N)  asm volatile("s_waitcnt vmcnt(" #N ")" ::: "memory")

#define STAGE(PTR, GROW0, BUF, MAT, KH, KBASE) do {                                   \
    const uint16_t* _g = (PTR) + (size_t)((GROW0) + (tid >> 2)) * KD                  \
                         + (KBASE) + (KH) * 32 + sslot * 8;                           \
    uint16_t* _d = lds + (((BUF) * 2 + (MAT)) * 2 + (KH)) * 8192 + wave * 512;        \
    GLDS16(_g, _d);                                                                   \
    GLDS16(_g + 128 * KD, _d + 4096);                                                 \
} while (0)

#define LOADA(P, KH, CH) do {                                                         \
    const uint16_t* _Ar = lds + (((P) * 2 + 0) * 2 + (KH)) * 8192;                    \
    _Pragma("unroll")                                                                 \
    for (int m = 0; m < 4; ++m)                                                       \
        a[m] = *(const bf16x8*)&_Ar[(wr * 128 + ((CH) * 4 + m) * 16 + lr) * 32 + sx * 8]; \
} while (0)

#define LOADB(P, KH) do {                                                             \
    const uint16_t* _Br = lds + (((P) * 2 + 1) * 2 + (KH)) * 8192;                    \
    _Pragma("unroll")                                                                 \
    for (int n = 0; n < 4; ++n)                                                       \
        b[n] = *(const bf16x8*)&_Br[(wc * 64 + n * 16 + lr) * 32 + sx * 8];           \
} while (0)

#define MFMAQ(CH) do {                                                                \
    __builtin_amdgcn_s_setprio(1);                                                    \
    _Pragma("unroll")                                                                 \
    for (int m = 0; m < 4; ++m)                                                       \
    _Pragma("unroll")                                                                 \
    for (int n = 0; n < 4; ++n)                                                       \
        acc[(CH) * 4 + m][n] = __builtin_amdgcn_mfma_f32_16x16x32_bf16(               \
            a[m], b[n], acc[(CH) * 4 + m][n], 0, 0, 0);                               \
    __builtin_amdgcn_s_setprio(0);                                                    \
} while (0)

__global__ __launch_bounds__(512, 2)
void gemm_kernel(const uint16_t* __restrict__ A,
                 const uint16_t* __restrict__ B,
                 float* __restrict__ C) {
    __shared__ uint16_t lds[65536];   // 128 KiB

    const int tid  = threadIdx.x;
    const int wave = tid >> 6;
    const int lane = tid & 63;
    const int wr = wave >> 2;                  // 0..1
    const int wc = wave & 3;                   // 0..3
    const int lr = lane & 15;
    const int ls = lane >> 4;
    const int sx = ls ^ ((lr >> 1) & 3);              // swizzled read slot
    const int sslot = (tid & 3) ^ ((tid >> 3) & 3);   // pre-swizzled stage source slot

    // XCD-aware swizzle: 256 wgs, 8 XCDs, 32 contiguous tiles per XCD
    int bid = blockIdx.x;
    int wg = (bid & 7) * 32 + (bid >> 3);
    const int bm0 = (wg >> 4) * 256;
    const int bn0 = (wg & 15) * 256;

    f32x4 acc[8][4];
#pragma unroll
    for (int m = 0; m < 8; ++m)
#pragma unroll
        for (int n = 0; n < 4; ++n) {
            f32x4 z = {0.f, 0.f, 0.f, 0.f};
            acc[m][n] = z;
        }

    // prologue: stage tile 0 fully into buf0 (order: Ak0, Bk0, Ak1, Bk1)
    STAGE(A, bm0, 0, 0, 0, 0);
    STAGE(B, bn0, 0, 1, 0, 0);
    STAGE(A, bm0, 0, 0, 1, 0);
    STAGE(B, bn0, 0, 1, 1, 0);
    VM(4);                      // k0 landed per-wave; k1 (4 loads) in flight
    BAR();                      // collectivize

#pragma unroll 1
    for (int t = 0; t < NT - 1; ++t) {
        const int p = t & 1, q = p ^ 1;
        const int kn = (t + 1) * BK;
        bf16x8 a[4], b[4];
        // phase 1: (k0, c0) + stage A-k0(t+1)
        LOADB(p, 0);
        LOADA(p, 0, 0);
        STAGE(A, bm0, q, 0, 0, kn);
        BAR(); LGKM0();
        MFMAQ(0);
        BAR();
        // phase 2: (k0, c1) + stage B-k0(t+1); then wait own k1 of tile t
        LOADA(p, 0, 1);
        STAGE(B, bn0, q, 1, 0, kn);
        BAR(); LGKM0();
        MFMAQ(1);
        VM(4);
        BAR();
        // phase 3: (k1, c0) + stage A-k1(t+1)
        LOADB(p, 1);
        LOADA(p, 1, 0);
        STAGE(A, bm0, q, 0, 1, kn);
        BAR(); LGKM0();
        MFMAQ(0);
        BAR();
        // phase 4: (k1, c1) + stage B-k1(t+1); wait k0 of tile t+1
        LOADA(p, 1, 1);
        STAGE(B, bn0, q, 1, 1, kn);
        BAR(); LGKM0();
        MFMAQ(1);
        VM(4);
        BAR();
    }
    // last tile t = NT-1 (p=1), no staging
    {
        const int p = (NT - 1) & 1;
        bf16x8 a[4], b[4];
        LOADB(p, 0);
        LOADA(p, 0, 0);
        BAR(); LGKM0();
        MFMAQ(0);
        BAR();
        LOADA(p, 0, 1);
        BAR(); LGKM0();
        MFMAQ(1);
        VM(0);                  // drain own k1 stages
        BAR();
        LOADB(p, 1);
        LOADA(p, 1, 0);
        BAR(); LGKM0();
        MFMAQ(0);
        BAR();
        LOADA(p, 1, 1);
        BAR(); LGKM0();
        MFMAQ(1);
    }

    // epilogue: D layout col=lane&15, row=(lane>>4)*4+r  [m89/m91]
    const int r0 = ls * 4;
#pragma unroll
    for (int m = 0; m < 8; ++m)
#pragma unroll
        for (int n = 0; n < 4; ++n)
#pragma unroll
            for (int r = 0; r < 4; ++r) {
                int row = bm0 + wr * 128 + m * 16 + r0 + r;
                int col = bn0 + wc * 64 + n * 16 + lr;
                C[(size_t)row * ND + col] = acc[m][n][r];
            }
}

extern "C" void kernel_launch(void* const* d_in, const int* in_sizes, int n_in,
                              void* d_out, int out_size, void* d_ws, size_t ws_size,
                              hipStream_t stream) {
    const float* x     = (const float*)d_in[0];
    const int*   Wq    = (const int*)d_in[1];
    const float* scale = (const float*)d_in[2];
    const float* zero  = (const float*)d_in[3];
    float* out = (float*)d_out;

    uint16_t* Wb = (uint16_t*)d_ws;                                     // 32 MB
    uint16_t* xb = (uint16_t*)((char*)d_ws + (size_t)32 * 1024 * 1024); // 32 MB

    hipLaunchKernelGGL(dq_kernel, dim3(4096), dim3(256), 0, stream, Wq, scale, zero, Wb);
    hipLaunchKernelGGL(xc_kernel, dim3(8192), dim3(256), 0, stream, x, xb);
    hipLaunchKernelGGL(gemm_kernel, dim3(256), dim3(512), 0, stream, xb, Wb, out);
}

// Round 4
// 148.090 us; speedup vs baseline: 1.3083x; 1.0188x over previous
//
#include <hip/hip_runtime.h>
#include <stdint.h>

#define MD 4096
#define ND 4096
#define KD 4096
#define BK 64
#define NT (KD / BK)   // 64 K-tiles

typedef __bf16 bf16x8 __attribute__((ext_vector_type(8)));
typedef float f32x4 __attribute__((ext_vector_type(4)));

__device__ __forceinline__ uint32_t f32_to_bf16(float f) {
    union { float f; uint32_t u; } v; v.f = f;
    return (v.u + 0x7FFFu + ((v.u >> 16) & 1u)) >> 16;
}

#define GLDS16(gp, lp) \
    __builtin_amdgcn_global_load_lds((const __attribute__((address_space(1))) void*)(gp), \
                                     (__attribute__((address_space(3))) void*)(lp), 16, 0, 0)

// ---------------------------------------------------------------------------
// Fused prelude: blocks [0,4096) dequant W_q (int32-widened packed bytes) to
// bf16 Wb[4096][4096]; blocks [4096,12288) convert x fp32->bf16.
// W row o<2048: high nibbles of Wq[o*4096+i]; row o>=2048: low nibbles.
// group g = o*64 + i/64.
// ---------------------------------------------------------------------------
__global__ void prep_kernel(const int* __restrict__ Wq,
                            const float* __restrict__ scale,
                            const float* __restrict__ zero,
                            const float* __restrict__ x,
                            uint16_t* __restrict__ Wb,
                            uint16_t* __restrict__ xb) {
    int blk = blockIdx.x;
    if (blk < 4096) {
        int t = blk * 256 + threadIdx.x;             // 1048576 threads
        int o  = t >> 9;
        int i0 = (t & 511) << 3;
        const uint4* wp = (const uint4*)Wq;
        uint4 pa = wp[t * 2], pb = wp[t * 2 + 1];
        uint32_t v[8] = {pa.x, pa.y, pa.z, pa.w, pb.x, pb.y, pb.z, pb.w};
        int gh = (o << 6) + (i0 >> 6);
        int gl = gh + (2048 << 6);
        float sh = scale[gh], zh = zero[gh];
        float sl = scale[gl], zl = zero[gl];
        uint32_t hw[4], lw[4];
#pragma unroll
        for (int p = 0; p < 4; ++p) {
            uint32_t b0 = v[p * 2], b1 = v[p * 2 + 1];
            uint32_t h0 = f32_to_bf16(((float)((b0 >> 4) & 15u) - zh) * sh);
            uint32_t h1 = f32_to_bf16(((float)((b1 >> 4) & 15u) - zh) * sh);
            uint32_t l0 = f32_to_bf16(((float)(b0 & 15u) - zl) * sl);
            uint32_t l1 = f32_to_bf16(((float)(b1 & 15u) - zl) * sl);
            hw[p] = h0 | (h1 << 16);
            lw[p] = l0 | (l1 << 16);
        }
        uint4 hv = {hw[0], hw[1], hw[2], hw[3]};
        uint4 lv = {lw[0], lw[1], lw[2], lw[3]};
        *(uint4*)&Wb[(size_t)o * KD + i0]          = hv;
        *(uint4*)&Wb[(size_t)(o + 2048) * KD + i0] = lv;
    } else {
        int t = (blk - 4096) * 256 + threadIdx.x;    // 2097152 threads
        const float4* xp = (const float4*)x;
        float4 a = xp[t * 2], b = xp[t * 2 + 1];
        uint4 o;
        o.x = f32_to_bf16(a.x) | (f32_to_bf16(a.y) << 16);
        o.y = f32_to_bf16(a.z) | (f32_to_bf16(a.w) << 16);
        o.z = f32_to_bf16(b.x) | (f32_to_bf16(b.y) << 16);
        o.w = f32_to_bf16(b.z) | (f32_to_bf16(b.w) << 16);
        ((uint4*)xb)[t] = o;
    }
}

// ---------------------------------------------------------------------------
// 256x256 tile, BK=64, 8 waves (2Mx4N, each 128x64), 4-phase/K-tile schedule.
// Only 2 load-bearing barriers per K-tile (VM(4);BAR at kh boundaries) —
// staging always targets the opposite buffer; cross-iter WAR hazards are two
// barriers apart; per-wave lgkmcnt covers own ds_reads. Waves de-lockstep
// within a 2-phase window so MFMA overlaps other waves' loads (T5 active).
// LDS region(buf,mat,kh) = 256 rows x 32 cols bf16 (16 KiB); 8 regions=128 KiB.
// ---------------------------------------------------------------------------
#define BAR()  asm volatile("s_barrier" ::: "memory")
#define LGKM0() do { asm volatile("s_waitcnt lgkmcnt(0)" ::: "memory"); \
                     __builtin_amdgcn_sched_barrier(0); } while (0)
#define VM(N)  asm volatile("s_waitcnt vmcnt(" #N ")" ::: "memory")

#define STAGE(PTR, GROW0, BUF, MAT, KH, KBASE) do {                                   \
    const uint16_t* _g = (PTR) + (size_t)((GROW0) + (tid >> 2)) * KD                  \
                         + (KBASE) + (KH) * 32 + sslot * 8;                           \
    uint16_t* _d = lds + (((BUF) * 2 + (MAT)) * 2 + (KH)) * 8192 + wave * 512;        \
    GLDS16(_g, _d);                                                                   \
    GLDS16(_g + 128 * KD, _d + 4096);                                                 \
} while (0)

#define LOADA(P, KH, CH) do {                                                         \
    const uint16_t* _Ar = lds + (((P) * 2 + 0) * 2 + (KH)) * 8192;                    \
    _Pragma("unroll")                                                                 \
    for (int m = 0; m < 4; ++m)                                                       \
        a[m] = *(const bf16x8*)&_Ar[(wr * 128 + ((CH) * 4 + m) * 16 + lr) * 32 + sx * 8]; \
} while (0)

#define LOADB(P, KH) do {                                                             \
    const uint16_t* _Br = lds + (((P) * 2 + 1) * 2 + (KH)) * 8192;                    \
    _Pragma("unroll")                                                                 \
    for (int n = 0; n < 4; ++n)                                                       \
        b[n] = *(const bf16x8*)&_Br[(wc * 64 + n * 16 + lr) * 32 + sx * 8];           \
} while (0)

#define MFMAQ(CH) do {                                                                \
    __builtin_amdgcn_s_setprio(1);                                                    \
    _Pragma("unroll")                                                                 \
    for (int m = 0; m < 4; ++m)                                                       \
    _Pragma("unroll")                                                                 \
    for (int n = 0; n < 4; ++n)                                                       \
        acc[(CH) * 4 + m][n] = __builtin_amdgcn_mfma_f32_16x16x32_bf16(               \
            a[m], b[n], acc[(CH) * 4 + m][n], 0, 0, 0);                               \
    __builtin_amdgcn_s_setprio(0);                                                    \
} while (0)

__global__ __launch_bounds__(512, 2)
void gemm_kernel(const uint16_t* __restrict__ A,
                 const uint16_t* __restrict__ B,
                 float* __restrict__ C) {
    __shared__ uint16_t lds[65536];   // 128 KiB

    const int tid  = threadIdx.x;
    const int wave = tid >> 6;
    const int lane = tid & 63;
    const int wr = wave >> 2;                  // 0..1
    const int wc = wave & 3;                   // 0..3
    const int lr = lane & 15;
    const int ls = lane >> 4;
    const int sx = ls ^ ((lr >> 1) & 3);              // swizzled read slot
    const int sslot = (tid & 3) ^ ((tid >> 3) & 3);   // pre-swizzled stage source slot

    // XCD-aware swizzle: 256 wgs, 8 XCDs, 32 contiguous tiles per XCD
    int bid = blockIdx.x;
    int wg = (bid & 7) * 32 + (bid >> 3);
    const int bm0 = (wg >> 4) * 256;
    const int bn0 = (wg & 15) * 256;

    f32x4 acc[8][4];
#pragma unroll
    for (int m = 0; m < 8; ++m)
#pragma unroll
        for (int n = 0; n < 4; ++n) {
            f32x4 z = {0.f, 0.f, 0.f, 0.f};
            acc[m][n] = z;
        }

    // prologue: stage tile 0 fully into buf0 (order: Ak0, Bk0, Ak1, Bk1)
    STAGE(A, bm0, 0, 0, 0, 0);
    STAGE(B, bn0, 0, 1, 0, 0);
    STAGE(A, bm0, 0, 0, 1, 0);
    STAGE(B, bn0, 0, 1, 1, 0);
    VM(4);                      // kh0 landed per-wave; kh1 (4 loads) in flight
    BAR();                      // collectivize

#pragma unroll 1
    for (int t = 0; t < NT - 1; ++t) {
        const int p = t & 1, q = p ^ 1;
        const int kn = (t + 1) * BK;
        bf16x8 a[4], b[4];
        // phase 1: (kh0, c0) + stage A-kh0(t+1)
        LOADB(p, 0);
        LOADA(p, 0, 0);
        STAGE(A, bm0, q, 0, 0, kn);
        LGKM0();
        MFMAQ(0);
        // phase 2: (kh0, c1) + stage B-kh0(t+1); then collectivized kh1 drain
        LOADA(p, 0, 1);
        STAGE(B, bn0, q, 1, 0, kn);
        LGKM0();
        MFMAQ(1);
        VM(4);
        BAR();
        // phase 3: (kh1, c0) + stage A-kh1(t+1)
        LOADB(p, 1);
        LOADA(p, 1, 0);
        STAGE(A, bm0, q, 0, 1, kn);
        LGKM0();
        MFMAQ(0);
        // phase 4: (kh1, c1) + stage B-kh1(t+1); collectivized kh0(t+1) drain
        LOADA(p, 1, 1);
        STAGE(B, bn0, q, 1, 1, kn);
        LGKM0();
        MFMAQ(1);
        VM(4);
        BAR();
    }
    // last tile t = NT-1 (p=1), no staging
    {
        const int p = (NT - 1) & 1;
        bf16x8 a[4], b[4];
        LOADB(p, 0);
        LOADA(p, 0, 0);
        LGKM0();
        MFMAQ(0);
        LOADA(p, 0, 1);
        LGKM0();
        MFMAQ(1);
        VM(0);                  // drain kh1 stages
        BAR();
        LOADB(p, 1);
        LOADA(p, 1, 0);
        LGKM0();
        MFMAQ(0);
        LOADA(p, 1, 1);
        LGKM0();
        MFMAQ(1);
    }

    // epilogue: D layout col=lane&15, row=(lane>>4)*4+r  [m89/m91]
    const int r0 = ls * 4;
#pragma unroll
    for (int m = 0; m < 8; ++m)
#pragma unroll
        for (int n = 0; n < 4; ++n)
#pragma unroll
            for (int r = 0; r < 4; ++r) {
                int row = bm0 + wr * 128 + m * 16 + r0 + r;
                int col = bn0 + wc * 64 + n * 16 + lr;
                C[(size_t)row * ND + col] = acc[m][n][r];
            }
}

extern "C" void kernel_launch(void* const* d_in, const int* in_sizes, int n_in,
                              void* d_out, int out_size, void* d_ws, size_t ws_size,
                              hipStream_t stream) {
    const float* x     = (const float*)d_in[0];
    const int*   Wq    = (const int*)d_in[1];
    const float* scale = (const float*)d_in[2];
    const float* zero  = (const float*)d_in[3];
    float* out = (float*)d_out;

    uint16_t* Wb = (uint16_t*)d_ws;                                     // 32 MB
    uint16_t* xb = (uint16_t*)((char*)d_ws + (size_t)32 * 1024 * 1024); // 32 MB

    hipLaunchKernelGGL(prep_kernel, dim3(12288), dim3(256), 0, stream,
                       Wq, scale, zero, x, Wb, xb);
    hipLaunchKernelGGL(gemm_kernel, dim3(256), dim3(512), 0, stream, xb, Wb, out);
}